// Round 6
// baseline (13184.694 us; speedup 1.0000x reference)
//
#include <hip/hip_runtime.h>
#include <math.h>

// Problem constants: B=8192, N=4096, D=2048, M=1024, C=64, K=100
#define LN_EPS 1e-6

// ---------------------------------------------------------------------------
// f32 tiled GEMM core: C[Mx,Nx] = A[Mx,Kx] @ B  (TRANSB: B is [Nx,Kx], use B^T)
// 128x128 tile, 256 threads, 8x8 microtile (4+4 split, 64-offset).
// Double-buffered LDS, register-staged issue-early/write-late global loads.
// Per-output-element FMA order identical to the round-4 kernel.
// ---------------------------------------------------------------------------
template <int TRANSB>
__device__ __forceinline__ void gemm128_body(const float* __restrict__ A,
                                             const float* __restrict__ B,
                                             float* __restrict__ C,
                                             int Mx, int Nx, int Kx,
                                             int bm, int bn,
                                             float (&As)[2][16][132],
                                             float (&Bs)[2][16][132]) {
  const int tid = threadIdx.x;
  const int ty = tid >> 4;  // 0..15
  const int tx = tid & 15;  // 0..15

  float4 aReg[2], bReg[2];

  auto loadA = [&](int k0) {
#pragma unroll
    for (int it = 0; it < 2; ++it) {
      const int idx = tid + it * 256;  // 0..511
      aReg[it] = *reinterpret_cast<const float4*>(
          A + (size_t)(bm + (idx >> 2)) * Kx + k0 + ((idx & 3) << 2));
    }
  };
  auto loadB = [&](int k0) {
    if (TRANSB) {
#pragma unroll
      for (int it = 0; it < 2; ++it) {
        const int idx = tid + it * 256;
        bReg[it] = *reinterpret_cast<const float4*>(
            B + (size_t)(bn + (idx >> 2)) * Kx + k0 + ((idx & 3) << 2));
      }
    } else {
#pragma unroll
      for (int it = 0; it < 2; ++it) {
        const int idx = tid + it * 256;
        bReg[it] = *reinterpret_cast<const float4*>(
            B + (size_t)(k0 + (idx >> 5)) * Nx + bn + ((idx & 31) << 2));
      }
    }
  };
  auto storeA = [&](int buf) {
#pragma unroll
    for (int it = 0; it < 2; ++it) {
      const int idx = tid + it * 256;
      const int r = idx >> 2, c4 = (idx & 3) << 2;
      As[buf][c4 + 0][r] = aReg[it].x;
      As[buf][c4 + 1][r] = aReg[it].y;
      As[buf][c4 + 2][r] = aReg[it].z;
      As[buf][c4 + 3][r] = aReg[it].w;
    }
  };
  auto storeB = [&](int buf) {
    if (TRANSB) {
#pragma unroll
      for (int it = 0; it < 2; ++it) {
        const int idx = tid + it * 256;
        const int r = idx >> 2, c4 = (idx & 3) << 2;
        Bs[buf][c4 + 0][r] = bReg[it].x;
        Bs[buf][c4 + 1][r] = bReg[it].y;
        Bs[buf][c4 + 2][r] = bReg[it].z;
        Bs[buf][c4 + 3][r] = bReg[it].w;
      }
    } else {
#pragma unroll
      for (int it = 0; it < 2; ++it) {
        const int idx = tid + it * 256;
        const int kr = idx >> 5, c4 = (idx & 31) << 2;
        *reinterpret_cast<float4*>(&Bs[buf][kr][c4]) = bReg[it];
      }
    }
  };

  float acc[2][2][4][4] = {};  // [rowHalf][colHalf][i][j]

  // prologue: stage tile 0
  loadA(0);
  loadB(0);
  storeA(0);
  storeB(0);
  __syncthreads();

  const int nk = Kx >> 4;
  for (int kt = 0; kt < nk; ++kt) {
    const int cur = kt & 1;
    if (kt + 1 < nk) {
      loadA((kt + 1) << 4);  // issue-early: HBM latency hides under the MACs below
      loadB((kt + 1) << 4);
    }
#pragma unroll
    for (int kk = 0; kk < 16; ++kk) {
      float a0[4], a1[4], b0[4], b1[4];
      *reinterpret_cast<float4*>(a0) = *reinterpret_cast<const float4*>(&As[cur][kk][ty * 4]);
      *reinterpret_cast<float4*>(a1) =
          *reinterpret_cast<const float4*>(&As[cur][kk][ty * 4 + 64]);
      *reinterpret_cast<float4*>(b0) = *reinterpret_cast<const float4*>(&Bs[cur][kk][tx * 4]);
      *reinterpret_cast<float4*>(b1) =
          *reinterpret_cast<const float4*>(&Bs[cur][kk][tx * 4 + 64]);
#pragma unroll
      for (int i = 0; i < 4; ++i)
#pragma unroll
        for (int j = 0; j < 4; ++j) {
          acc[0][0][i][j] = fmaf(a0[i], b0[j], acc[0][0][i][j]);
          acc[0][1][i][j] = fmaf(a0[i], b1[j], acc[0][1][i][j]);
          acc[1][0][i][j] = fmaf(a1[i], b0[j], acc[1][0][i][j]);
          acc[1][1][i][j] = fmaf(a1[i], b1[j], acc[1][1][i][j]);
        }
    }
    if (kt + 1 < nk) {
      __syncthreads();  // all waves done reading buf[cur^1]
      storeA(cur ^ 1);  // write-late: vmcnt drain lands here, off the read path
      storeB(cur ^ 1);
      __syncthreads();
    }
  }

#pragma unroll
  for (int ri = 0; ri < 2; ++ri)
#pragma unroll
    for (int i = 0; i < 4; ++i) {
      const size_t row = (size_t)(bm + ri * 64 + ty * 4 + i);
#pragma unroll
      for (int ci = 0; ci < 2; ++ci) {
        float4 o = make_float4(acc[ri][ci][i][0], acc[ri][ci][i][1], acc[ri][ci][i][2],
                               acc[ri][ci][i][3]);
        *reinterpret_cast<float4*>(C + row * Nx + bn + ci * 64 + tx * 4) = o;
      }
    }
}

template <int TRANSB>
__global__ __launch_bounds__(256, 2) void gemm128db(const float* __restrict__ A,
                                                    const float* __restrict__ B,
                                                    float* __restrict__ C,
                                                    int Mx, int Nx, int Kx) {
  __shared__ float As[2][16][132];
  __shared__ float Bs[2][16][132];
  gemm128_body<TRANSB>(A, B, C, Mx, Nx, Kx, blockIdx.y * 128, blockIdx.x * 128, As, Bs);
}

// Fused k&v projection: blockIdx.z selects {W_k->k, W_v->v}. Doubles the grid
// (256 -> 512 blocks = 2 blocks/CU) with bitwise-identical per-element math.
__global__ __launch_bounds__(256, 2) void gemm128db_kv(const float* __restrict__ A,
                                                       const float* __restrict__ W_k,
                                                       const float* __restrict__ W_v,
                                                       float* __restrict__ k,
                                                       float* __restrict__ v,
                                                       int Mx, int Nx, int Kx) {
  __shared__ float As[2][16][132];
  __shared__ float Bs[2][16][132];
  const float* B = (blockIdx.z == 0) ? W_k : W_v;
  float* C = (blockIdx.z == 0) ? k : v;
  gemm128_body<0>(A, B, C, Mx, Nx, Kx, blockIdx.y * 128, blockIdx.x * 128, As, Bs);
}

// ---------------------------------------------------------------------------
// Row softmax over N=4096 with the 1/sqrt(M)=1/32 score scale folded in.
// ---------------------------------------------------------------------------
__global__ __launch_bounds__(256) void softmax_rows(float* __restrict__ S) {
  const size_t row = blockIdx.x;
  float* p = S + row * 4096;
  const int tid = threadIdx.x;
  const int wid = tid >> 6, lane = tid & 63;
  __shared__ float red[4];

  float x[16];
#pragma unroll
  for (int i = 0; i < 4; ++i) {
    float4 v = *reinterpret_cast<const float4*>(p + i * 1024 + tid * 4);
    x[i * 4 + 0] = v.x;
    x[i * 4 + 1] = v.y;
    x[i * 4 + 2] = v.z;
    x[i * 4 + 3] = v.w;
  }
  float m = x[0];
#pragma unroll
  for (int i = 1; i < 16; ++i) m = fmaxf(m, x[i]);
  for (int off = 32; off; off >>= 1) m = fmaxf(m, __shfl_xor(m, off));
  if (lane == 0) red[wid] = m;
  __syncthreads();
  if (tid == 0) red[0] = fmaxf(fmaxf(red[0], red[1]), fmaxf(red[2], red[3]));
  __syncthreads();
  m = red[0];

  const float sc = 0.03125f;  // 1/sqrt(1024)
  float e[16];
  float s = 0.f;
#pragma unroll
  for (int i = 0; i < 16; ++i) {
    e[i] = expf((x[i] - m) * sc);
    s += e[i];
  }
  for (int off = 32; off; off >>= 1) s += __shfl_xor(s, off);
  if (lane == 0) red[wid] = s;
  __syncthreads();
  if (tid == 0) red[0] = red[0] + red[1] + red[2] + red[3];
  __syncthreads();
  const float inv = 1.f / red[0];

#pragma unroll
  for (int i = 0; i < 4; ++i) {
    float4 v = make_float4(e[i * 4 + 0] * inv, e[i * 4 + 1] * inv, e[i * 4 + 2] * inv,
                           e[i * 4 + 3] * inv);
    *reinterpret_cast<float4*>(p + i * 1024 + tid * 4) = v;
  }
}

// ---------------------------------------------------------------------------
// attended = attRaw*0.1 + q, then LayerNorm over M=1024 (f64 statistics).
// ---------------------------------------------------------------------------
__global__ __launch_bounds__(256) void ln_resid(const float* __restrict__ attRaw,
                                                const float* __restrict__ q,
                                                const float* __restrict__ gamma,
                                                const float* __restrict__ beta,
                                                float* __restrict__ out) {
  const size_t row = blockIdx.x;
  const int tid = threadIdx.x;
  const int wid = tid >> 6, lane = tid & 63;
  __shared__ double redd[4];

  float4 a = *reinterpret_cast<const float4*>(attRaw + row * 1024 + tid * 4);
  float4 qq = *reinterpret_cast<const float4*>(q + row * 1024 + tid * 4);
  float x[4];
  x[0] = fmaf(0.1f, a.x, qq.x);
  x[1] = fmaf(0.1f, a.y, qq.y);
  x[2] = fmaf(0.1f, a.z, qq.z);
  x[3] = fmaf(0.1f, a.w, qq.w);

  double s = (double)x[0] + (double)x[1] + (double)x[2] + (double)x[3];
  for (int off = 32; off; off >>= 1) s += __shfl_xor(s, off);
  if (lane == 0) redd[wid] = s;
  __syncthreads();
  if (tid == 0) redd[0] = redd[0] + redd[1] + redd[2] + redd[3];
  __syncthreads();
  const double mu = redd[0] * (1.0 / 1024.0);
  __syncthreads();

  double d2 = 0.0;
#pragma unroll
  for (int i = 0; i < 4; ++i) {
    double d = (double)x[i] - mu;
    d2 += d * d;
  }
  for (int off = 32; off; off >>= 1) d2 += __shfl_xor(d2, off);
  if (lane == 0) redd[wid] = d2;
  __syncthreads();
  if (tid == 0) redd[0] = redd[0] + redd[1] + redd[2] + redd[3];
  __syncthreads();
  const double var = redd[0] * (1.0 / 1024.0);
  const float rs = (float)(1.0 / sqrt(var + (double)LN_EPS));
  const float muf = (float)mu;

  float4 g = *reinterpret_cast<const float4*>(gamma + tid * 4);
  float4 bb = *reinterpret_cast<const float4*>(beta + tid * 4);
  float4 o;
  o.x = fmaf((x[0] - muf) * rs, g.x, bb.x);
  o.y = fmaf((x[1] - muf) * rs, g.y, bb.y);
  o.z = fmaf((x[2] - muf) * rs, g.z, bb.z);
  o.w = fmaf((x[3] - muf) * rs, g.w, bb.w);
  *reinterpret_cast<float4*>(out + row * 1024 + tid * 4) = o;
}

// ---------------------------------------------------------------------------
// Head: fc_hash = normed @ W_hash + b_hash (f64 accumulate — sign decides the
// straight-through bit), sigmoid, binarize, fc_cls = code @ W_cls + b_cls.
// ---------------------------------------------------------------------------
__global__ __launch_bounds__(128) void head_kernel(const float* __restrict__ normed,
                                                   const float* __restrict__ W_hash,
                                                   const float* __restrict__ b_hash,
                                                   const float* __restrict__ W_cls,
                                                   const float* __restrict__ b_cls,
                                                   float* __restrict__ out_code,
                                                   float* __restrict__ out_prob,
                                                   float* __restrict__ out_cls) {
  __shared__ float ns[1024];
  __shared__ float cs[64];
  const size_t b = blockIdx.x;
  const int tid = threadIdx.x;

#pragma unroll
  for (int i = 0; i < 2; ++i) {
    const int idx = (tid + i * 128) * 4;
    *reinterpret_cast<float4*>(&ns[idx]) =
        *reinterpret_cast<const float4*>(normed + b * 1024 + idx);
  }
  __syncthreads();

  if (tid < 64) {
    double acc = 0.0;
#pragma unroll 4
    for (int m = 0; m < 1024; ++m)
      acc = fma((double)ns[m], (double)W_hash[m * 64 + tid], acc);
    const float fc = (float)(acc + (double)b_hash[tid]);
    const float pr = 1.f / (1.f + expf(-fc));
    const float code = fc > 0.f ? 1.f : 0.f;  // prob>0.5 <=> fc_hash>0
    out_code[b * 64 + tid] = code;
    out_prob[b * 64 + tid] = pr;
    cs[tid] = code;
  }
  __syncthreads();

  if (tid < 100) {
    float acc = b_cls[tid];
#pragma unroll 8
    for (int c = 0; c < 64; ++c)
      if (cs[c] != 0.f) acc += W_cls[c * 100 + tid];
    out_cls[b * 100 + tid] = acc;
  }
}

// ---------------------------------------------------------------------------
extern "C" void kernel_launch(void* const* d_in, const int* in_sizes, int n_in,
                              void* d_out, int out_size, void* d_ws, size_t ws_size,
                              hipStream_t stream) {
  const float* feat = (const float*)d_in[0];    // [8192,2048]
  const float* emb = (const float*)d_in[1];     // [4096,2048]
  const float* W_k = (const float*)d_in[2];     // [2048,1024]
  const float* W_v = (const float*)d_in[3];
  const float* W_q = (const float*)d_in[4];
  const float* W_hash = (const float*)d_in[5];  // [1024,64]
  const float* b_hash = (const float*)d_in[6];  // [64]
  const float* ln_g = (const float*)d_in[7];    // [1024]
  const float* ln_b = (const float*)d_in[8];
  const float* W_cls = (const float*)d_in[9];   // [64,100]
  const float* b_cls = (const float*)d_in[10];  // [100]
  float* out = (float*)d_out;

  const int B = 8192, N = 4096, D = 2048, M = 1024;

  // Workspace layout (floats): k [N*M] | v [N*M] | q [B*M] | S [chunk*N] | attRaw [B*M]
  float* ws = (float*)d_ws;
  float* k = ws;
  float* v = k + (size_t)N * M;
  float* q = v + (size_t)N * M;
  float* S = q + (size_t)B * M;

  const size_t fixed = (size_t)2 * N * M + (size_t)2 * B * M;  // k,v,q,attRaw
  const size_t avail = ws_size / sizeof(float);
  int chunk = 8192;  // prefer one attention pass; auto-shrink if ws is small
  while (chunk > 128 && fixed + (size_t)chunk * N > avail) chunk >>= 1;
  float* att = S + (size_t)chunk * N;

  // Projections: k & v fused (512 blocks = 2/CU), q separate (512 blocks)
  gemm128db_kv<<<dim3(M / 128, N / 128, 2), 256, 0, stream>>>(emb, W_k, W_v, k, v, N, M, D);
  gemm128db<0><<<dim3(M / 128, B / 128), 256, 0, stream>>>(feat, W_q, q, B, M, D);

  // Attention, chunked over rows of B
  for (int c0 = 0; c0 < B; c0 += chunk) {
    const float* qc = q + (size_t)c0 * M;
    gemm128db<1><<<dim3(N / 128, chunk / 128), 256, 0, stream>>>(qc, k, S, chunk, N, M);
    softmax_rows<<<chunk, 256, 0, stream>>>(S);
    gemm128db<0><<<dim3(M / 128, chunk / 128), 256, 0, stream>>>(S, v, att + (size_t)c0 * M,
                                                                 chunk, M, N);
  }

  // Residual + LayerNorm (in-place over attRaw)
  ln_resid<<<B, 256, 0, stream>>>(att, q, ln_g, ln_b, att);

  // Hash head + classifier
  head_kernel<<<B, 128, 0, stream>>>(att, W_hash, b_hash, W_cls, b_cls, out,
                                     out + (size_t)B * 64, out + (size_t)B * 128);
}

// Round 7
// 2701.708 us; speedup vs baseline: 4.8801x; 4.8801x over previous
//
#include <hip/hip_runtime.h>
#include <math.h>

// Problem constants: B=8192, N=4096, D=2048, M=1024, C=64, K=100
#define LN_EPS 1e-6

// ---------------------------------------------------------------------------
// f32 tiled GEMM: C[Mx,Nx] = A[Mx,Kx] @ B   (TRANSB: B given as [Nx,Kx], use B^T)
// 128x128 block tile, 256 threads, 8x8 microtile per thread (split 4+4 with a
// 64-element offset). K-step 16, single-buffered (proven round-4 codegen:
// 72 VGPR, no scratch). Occupancy comes from >=2 blocks/CU grid shaping.
// ---------------------------------------------------------------------------
template <int TRANSB>
__global__ __launch_bounds__(256) void gemm128(const float* __restrict__ A,
                                               const float* __restrict__ B,
                                               float* __restrict__ C,
                                               int Mx, int Nx, int Kx) {
  __shared__ float As[16][132];  // [k][m]
  __shared__ float Bs[16][132];  // [k][n]
  const int tid = threadIdx.x;
  const int bm = blockIdx.y * 128;
  const int bn = blockIdx.x * 128;
  const int ty = tid >> 4;   // 0..15
  const int tx = tid & 15;   // 0..15

  float acc[2][2][4][4] = {};  // [rowHalf][colHalf][i][j]

  for (int k0 = 0; k0 < Kx; k0 += 16) {
#pragma unroll
    for (int it = 0; it < 2; ++it) {
      const int idx = tid + it * 256;     // 0..511
      const int r = idx >> 2;             // 0..127
      const int c4 = (idx & 3) << 2;      // 0,4,8,12
      float4 av = *reinterpret_cast<const float4*>(A + (size_t)(bm + r) * Kx + k0 + c4);
      As[c4 + 0][r] = av.x;
      As[c4 + 1][r] = av.y;
      As[c4 + 2][r] = av.z;
      As[c4 + 3][r] = av.w;
    }
    if (TRANSB) {
#pragma unroll
      for (int it = 0; it < 2; ++it) {
        const int idx = tid + it * 256;
        const int r = idx >> 2;           // n index 0..127
        const int c4 = (idx & 3) << 2;    // k offset
        float4 bv = *reinterpret_cast<const float4*>(B + (size_t)(bn + r) * Kx + k0 + c4);
        Bs[c4 + 0][r] = bv.x;
        Bs[c4 + 1][r] = bv.y;
        Bs[c4 + 2][r] = bv.z;
        Bs[c4 + 3][r] = bv.w;
      }
    } else {
#pragma unroll
      for (int it = 0; it < 2; ++it) {
        const int idx = tid + it * 256;
        const int kr = idx >> 5;           // 0..15
        const int c4 = (idx & 31) << 2;    // 0..124
        float4 bv = *reinterpret_cast<const float4*>(B + (size_t)(k0 + kr) * Nx + bn + c4);
        *reinterpret_cast<float4*>(&Bs[kr][c4]) = bv;
      }
    }
    __syncthreads();

#pragma unroll
    for (int kk = 0; kk < 16; ++kk) {
      float a0[4], a1[4], b0[4], b1[4];
      *reinterpret_cast<float4*>(a0) = *reinterpret_cast<const float4*>(&As[kk][ty * 4]);
      *reinterpret_cast<float4*>(a1) = *reinterpret_cast<const float4*>(&As[kk][ty * 4 + 64]);
      *reinterpret_cast<float4*>(b0) = *reinterpret_cast<const float4*>(&Bs[kk][tx * 4]);
      *reinterpret_cast<float4*>(b1) = *reinterpret_cast<const float4*>(&Bs[kk][tx * 4 + 64]);
#pragma unroll
      for (int i = 0; i < 4; ++i)
#pragma unroll
        for (int j = 0; j < 4; ++j) {
          acc[0][0][i][j] = fmaf(a0[i], b0[j], acc[0][0][i][j]);
          acc[0][1][i][j] = fmaf(a0[i], b1[j], acc[0][1][i][j]);
          acc[1][0][i][j] = fmaf(a1[i], b0[j], acc[1][0][i][j]);
          acc[1][1][i][j] = fmaf(a1[i], b1[j], acc[1][1][i][j]);
        }
    }
    __syncthreads();
  }

#pragma unroll
  for (int ri = 0; ri < 2; ++ri)
#pragma unroll
    for (int i = 0; i < 4; ++i) {
      const size_t row = (size_t)(bm + ri * 64 + ty * 4 + i);
#pragma unroll
      for (int ci = 0; ci < 2; ++ci) {
        float4 o = make_float4(acc[ri][ci][i][0], acc[ri][ci][i][1], acc[ri][ci][i][2],
                               acc[ri][ci][i][3]);
        *reinterpret_cast<float4*>(C + row * Nx + bn + ci * 64 + tx * 4) = o;
      }
    }
}

// ---------------------------------------------------------------------------
// Fused k & v projections: identical body to gemm128<0>, blockIdx.z selects
// {W_k -> k, W_v -> v}. Doubles the grid (256 -> 512 blocks = 2 blocks/CU);
// per-element math bitwise identical to separate dispatches.
// ---------------------------------------------------------------------------
__global__ __launch_bounds__(256) void gemm128_kv(const float* __restrict__ A,
                                                  const float* __restrict__ W_k,
                                                  const float* __restrict__ W_v,
                                                  float* __restrict__ kOut,
                                                  float* __restrict__ vOut,
                                                  int Mx, int Nx, int Kx) {
  const float* __restrict__ B = (blockIdx.z == 0) ? W_k : W_v;
  float* __restrict__ C = (blockIdx.z == 0) ? kOut : vOut;

  __shared__ float As[16][132];
  __shared__ float Bs[16][132];
  const int tid = threadIdx.x;
  const int bm = blockIdx.y * 128;
  const int bn = blockIdx.x * 128;
  const int ty = tid >> 4;
  const int tx = tid & 15;

  float acc[2][2][4][4] = {};

  for (int k0 = 0; k0 < Kx; k0 += 16) {
#pragma unroll
    for (int it = 0; it < 2; ++it) {
      const int idx = tid + it * 256;
      const int r = idx >> 2;
      const int c4 = (idx & 3) << 2;
      float4 av = *reinterpret_cast<const float4*>(A + (size_t)(bm + r) * Kx + k0 + c4);
      As[c4 + 0][r] = av.x;
      As[c4 + 1][r] = av.y;
      As[c4 + 2][r] = av.z;
      As[c4 + 3][r] = av.w;
    }
#pragma unroll
    for (int it = 0; it < 2; ++it) {
      const int idx = tid + it * 256;
      const int kr = idx >> 5;
      const int c4 = (idx & 31) << 2;
      float4 bv = *reinterpret_cast<const float4*>(B + (size_t)(k0 + kr) * Nx + bn + c4);
      *reinterpret_cast<float4*>(&Bs[kr][c4]) = bv;
    }
    __syncthreads();

#pragma unroll
    for (int kk = 0; kk < 16; ++kk) {
      float a0[4], a1[4], b0[4], b1[4];
      *reinterpret_cast<float4*>(a0) = *reinterpret_cast<const float4*>(&As[kk][ty * 4]);
      *reinterpret_cast<float4*>(a1) = *reinterpret_cast<const float4*>(&As[kk][ty * 4 + 64]);
      *reinterpret_cast<float4*>(b0) = *reinterpret_cast<const float4*>(&Bs[kk][tx * 4]);
      *reinterpret_cast<float4*>(b1) = *reinterpret_cast<const float4*>(&Bs[kk][tx * 4 + 64]);
#pragma unroll
      for (int i = 0; i < 4; ++i)
#pragma unroll
        for (int j = 0; j < 4; ++j) {
          acc[0][0][i][j] = fmaf(a0[i], b0[j], acc[0][0][i][j]);
          acc[0][1][i][j] = fmaf(a0[i], b1[j], acc[0][1][i][j]);
          acc[1][0][i][j] = fmaf(a1[i], b0[j], acc[1][0][i][j]);
          acc[1][1][i][j] = fmaf(a1[i], b1[j], acc[1][1][i][j]);
        }
    }
    __syncthreads();
  }

#pragma unroll
  for (int ri = 0; ri < 2; ++ri)
#pragma unroll
    for (int i = 0; i < 4; ++i) {
      const size_t row = (size_t)(bm + ri * 64 + ty * 4 + i);
#pragma unroll
      for (int ci = 0; ci < 2; ++ci) {
        float4 o = make_float4(acc[ri][ci][i][0], acc[ri][ci][i][1], acc[ri][ci][i][2],
                               acc[ri][ci][i][3]);
        *reinterpret_cast<float4*>(C + row * Nx + bn + ci * 64 + tx * 4) = o;
      }
    }
}

// ---------------------------------------------------------------------------
// Row softmax over N=4096 with the 1/sqrt(M)=1/32 score scale folded in.
// ---------------------------------------------------------------------------
__global__ __launch_bounds__(256) void softmax_rows(float* __restrict__ S) {
  const size_t row = blockIdx.x;
  float* p = S + row * 4096;
  const int tid = threadIdx.x;
  const int wid = tid >> 6, lane = tid & 63;
  __shared__ float red[4];

  float x[16];
#pragma unroll
  for (int i = 0; i < 4; ++i) {
    float4 v = *reinterpret_cast<const float4*>(p + i * 1024 + tid * 4);
    x[i * 4 + 0] = v.x;
    x[i * 4 + 1] = v.y;
    x[i * 4 + 2] = v.z;
    x[i * 4 + 3] = v.w;
  }
  float m = x[0];
#pragma unroll
  for (int i = 1; i < 16; ++i) m = fmaxf(m, x[i]);
  for (int off = 32; off; off >>= 1) m = fmaxf(m, __shfl_xor(m, off));
  if (lane == 0) red[wid] = m;
  __syncthreads();
  if (tid == 0) red[0] = fmaxf(fmaxf(red[0], red[1]), fmaxf(red[2], red[3]));
  __syncthreads();
  m = red[0];

  const float sc = 0.03125f;  // 1/sqrt(1024)
  float e[16];
  float s = 0.f;
#pragma unroll
  for (int i = 0; i < 16; ++i) {
    e[i] = expf((x[i] - m) * sc);
    s += e[i];
  }
  for (int off = 32; off; off >>= 1) s += __shfl_xor(s, off);
  if (lane == 0) red[wid] = s;
  __syncthreads();
  if (tid == 0) red[0] = red[0] + red[1] + red[2] + red[3];
  __syncthreads();
  const float inv = 1.f / red[0];

#pragma unroll
  for (int i = 0; i < 4; ++i) {
    float4 v = make_float4(e[i * 4 + 0] * inv, e[i * 4 + 1] * inv, e[i * 4 + 2] * inv,
                           e[i * 4 + 3] * inv);
    *reinterpret_cast<float4*>(p + i * 1024 + tid * 4) = v;
  }
}

// ---------------------------------------------------------------------------
// attended = attRaw*0.1 + q, then LayerNorm over M=1024 (f64 statistics).
// ---------------------------------------------------------------------------
__global__ __launch_bounds__(256) void ln_resid(const float* __restrict__ attRaw,
                                                const float* __restrict__ q,
                                                const float* __restrict__ gamma,
                                                const float* __restrict__ beta,
                                                float* __restrict__ out) {
  const size_t row = blockIdx.x;
  const int tid = threadIdx.x;
  const int wid = tid >> 6, lane = tid & 63;
  __shared__ double redd[4];

  float4 a = *reinterpret_cast<const float4*>(attRaw + row * 1024 + tid * 4);
  float4 qq = *reinterpret_cast<const float4*>(q + row * 1024 + tid * 4);
  float x[4];
  x[0] = fmaf(0.1f, a.x, qq.x);
  x[1] = fmaf(0.1f, a.y, qq.y);
  x[2] = fmaf(0.1f, a.z, qq.z);
  x[3] = fmaf(0.1f, a.w, qq.w);

  double s = (double)x[0] + (double)x[1] + (double)x[2] + (double)x[3];
  for (int off = 32; off; off >>= 1) s += __shfl_xor(s, off);
  if (lane == 0) redd[wid] = s;
  __syncthreads();
  if (tid == 0) redd[0] = redd[0] + redd[1] + redd[2] + redd[3];
  __syncthreads();
  const double mu = redd[0] * (1.0 / 1024.0);
  __syncthreads();

  double d2 = 0.0;
#pragma unroll
  for (int i = 0; i < 4; ++i) {
    double d = (double)x[i] - mu;
    d2 += d * d;
  }
  for (int off = 32; off; off >>= 1) d2 += __shfl_xor(d2, off);
  if (lane == 0) redd[wid] = d2;
  __syncthreads();
  if (tid == 0) redd[0] = redd[0] + redd[1] + redd[2] + redd[3];
  __syncthreads();
  const double var = redd[0] * (1.0 / 1024.0);
  const float rs = (float)(1.0 / sqrt(var + (double)LN_EPS));
  const float muf = (float)mu;

  float4 g = *reinterpret_cast<const float4*>(gamma + tid * 4);
  float4 bb = *reinterpret_cast<const float4*>(beta + tid * 4);
  float4 o;
  o.x = fmaf((x[0] - muf) * rs, g.x, bb.x);
  o.y = fmaf((x[1] - muf) * rs, g.y, bb.y);
  o.z = fmaf((x[2] - muf) * rs, g.z, bb.z);
  o.w = fmaf((x[3] - muf) * rs, g.w, bb.w);
  *reinterpret_cast<float4*>(out + row * 1024 + tid * 4) = o;
}

// ---------------------------------------------------------------------------
// Head: fc_hash = normed @ W_hash + b_hash (f64 accumulate — sign decides the
// straight-through bit), sigmoid, binarize, fc_cls = code @ W_cls + b_cls.
// ---------------------------------------------------------------------------
__global__ __launch_bounds__(128) void head_kernel(const float* __restrict__ normed,
                                                   const float* __restrict__ W_hash,
                                                   const float* __restrict__ b_hash,
                                                   const float* __restrict__ W_cls,
                                                   const float* __restrict__ b_cls,
                                                   float* __restrict__ out_code,
                                                   float* __restrict__ out_prob,
                                                   float* __restrict__ out_cls) {
  __shared__ float ns[1024];
  __shared__ float cs[64];
  const size_t b = blockIdx.x;
  const int tid = threadIdx.x;

#pragma unroll
  for (int i = 0; i < 2; ++i) {
    const int idx = (tid + i * 128) * 4;
    *reinterpret_cast<float4*>(&ns[idx]) =
        *reinterpret_cast<const float4*>(normed + b * 1024 + idx);
  }
  __syncthreads();

  if (tid < 64) {
    double acc = 0.0;
#pragma unroll 4
    for (int m = 0; m < 1024; ++m)
      acc = fma((double)ns[m], (double)W_hash[m * 64 + tid], acc);
    const float fc = (float)(acc + (double)b_hash[tid]);
    const float pr = 1.f / (1.f + expf(-fc));
    const float code = fc > 0.f ? 1.f : 0.f;  // prob>0.5 <=> fc_hash>0
    out_code[b * 64 + tid] = code;
    out_prob[b * 64 + tid] = pr;
    cs[tid] = code;
  }
  __syncthreads();

  if (tid < 100) {
    float acc = b_cls[tid];
#pragma unroll 8
    for (int c = 0; c < 64; ++c)
      if (cs[c] != 0.f) acc += W_cls[c * 100 + tid];
    out_cls[b * 100 + tid] = acc;
  }
}

// ---------------------------------------------------------------------------
extern "C" void kernel_launch(void* const* d_in, const int* in_sizes, int n_in,
                              void* d_out, int out_size, void* d_ws, size_t ws_size,
                              hipStream_t stream) {
  const float* feat = (const float*)d_in[0];    // [8192,2048]
  const float* emb = (const float*)d_in[1];     // [4096,2048]
  const float* W_k = (const float*)d_in[2];     // [2048,1024]
  const float* W_v = (const float*)d_in[3];
  const float* W_q = (const float*)d_in[4];
  const float* W_hash = (const float*)d_in[5];  // [1024,64]
  const float* b_hash = (const float*)d_in[6];  // [64]
  const float* ln_g = (const float*)d_in[7];    // [1024]
  const float* ln_b = (const float*)d_in[8];
  const float* W_cls = (const float*)d_in[9];   // [64,100]
  const float* b_cls = (const float*)d_in[10];  // [100]
  float* out = (float*)d_out;

  const int B = 8192, N = 4096, D = 2048, M = 1024;

  // Workspace layout (floats): k [N*M] | v [N*M] | q [B*M] | S [chunk*N] | attRaw [B*M]
  float* ws = (float*)d_ws;
  float* k = ws;
  float* v = k + (size_t)N * M;
  float* q = v + (size_t)N * M;
  float* S = q + (size_t)B * M;

  const size_t fixed = (size_t)2 * N * M + (size_t)2 * B * M;  // k,v,q,attRaw
  const size_t avail = ws_size / sizeof(float);
  int chunk = 8192;  // one attention pass if ws allows (QK^T: 2048 blocks = 8/CU)
  while (chunk > 128 && fixed + (size_t)chunk * N > avail) chunk >>= 1;
  float* att = S + (size_t)chunk * N;

  // Projections: k & v fused (512 blocks = 2 blocks/CU), q (512 blocks)
  gemm128_kv<<<dim3(M / 128, N / 128, 2), 256, 0, stream>>>(emb, W_k, W_v, k, v, N, M, D);
  gemm128<0><<<dim3(M / 128, B / 128), 256, 0, stream>>>(feat, W_q, q, B, M, D);

  // Attention, chunked over rows of B
  for (int c0 = 0; c0 < B; c0 += chunk) {
    const float* qc = q + (size_t)c0 * M;
    gemm128<1><<<dim3(N / 128, chunk / 128), 256, 0, stream>>>(qc, k, S, chunk, N, M);
    softmax_rows<<<chunk, 256, 0, stream>>>(S);
    gemm128<0><<<dim3(M / 128, chunk / 128), 256, 0, stream>>>(S, v, att + (size_t)c0 * M,
                                                               chunk, M, N);
  }

  // Residual + LayerNorm (in-place over attRaw)
  ln_resid<<<B, 256, 0, stream>>>(att, q, ln_g, ln_b, att);

  // Hash head + classifier
  head_kernel<<<B, 128, 0, stream>>>(att, W_hash, b_hash, W_cls, b_cls, out,
                                     out + (size_t)B * 64, out + (size_t)B * 128);
}